// Round 2
// baseline (22628.557 us; speedup 1.0000x reference)
//
#include <hip/hip_runtime.h>
#include <hip/hip_bf16.h>

#define B_   128
#define T_   512
#define D_   512
#define U_   1024
#define O_   512
#define K_   1536      // D + U
#define G4U_ 4096
#define NBLK 128
#define APITCH 1544    // LDS A-row pitch in shorts (1536 + 8 pad -> dword stride 772 = 24*32+4)

typedef __attribute__((ext_vector_type(8))) short short8;
typedef __attribute__((ext_vector_type(4))) float f32x4;

__device__ __align__(16) unsigned short g_xbf[(size_t)B_ * T_ * D_];   // x as bf16 [b][t][d]
__device__ __align__(16) unsigned short g_Wt[(size_t)G4U_ * K_];       // W^T gate-grouped [cg][k]
__device__ __align__(16) unsigned short g_Wdt[(size_t)O_ * U_];        // Wd^T [o][u]
__device__ __align__(16) unsigned short g_h[2][(size_t)B_ * U_];       // double-buffered h (bf16)
__device__ unsigned int g_arrive[NBLK * 32];                            // 1 word per 128 B line
__device__ unsigned int g_release;

__device__ __forceinline__ unsigned short f2b(float f) {
  unsigned u = __float_as_uint(f);
  u += 0x7fffu + ((u >> 16) & 1u);   // RNE
  return (unsigned short)(u >> 16);
}

__global__ void prep_kernel(const float* __restrict__ x, const float* __restrict__ h0,
                            const float* __restrict__ kern, const float* __restrict__ rkern,
                            const float* __restrict__ Wd) {
  size_t tid = (size_t)blockIdx.x * blockDim.x + threadIdx.x;
  size_t np  = (size_t)gridDim.x * blockDim.x;
  if (tid < NBLK * 32) g_arrive[tid] = 0u;
  if (tid == 0) g_release = 0u;

  // x -> bf16
  const size_t nx8 = (size_t)B_ * T_ * D_ / 8;
  const float4* xv = (const float4*)x;
  for (size_t i = tid; i < nx8; i += np) {
    float4 v0 = xv[2 * i], v1 = xv[2 * i + 1];
    unsigned short tmp[8];
    tmp[0] = f2b(v0.x); tmp[1] = f2b(v0.y); tmp[2] = f2b(v0.z); tmp[3] = f2b(v0.w);
    tmp[4] = f2b(v1.x); tmp[5] = f2b(v1.y); tmp[6] = f2b(v1.z); tmp[7] = f2b(v1.w);
    *(int4*)&g_xbf[i * 8] = *(const int4*)tmp;
  }

  // Combined weights: stored row cg = (u>>4)*64 + gate*16 + (u&15); k contiguous.
  // (verified layout from round 1)
  const size_t nw = (size_t)G4U_ * (K_ / 8);
  for (size_t i = tid; i < nw; i += np) {
    size_t cg = i / (K_ / 8);
    int kb = (int)(i % (K_ / 8)) * 8;
    int c = (int)(cg >> 6), g = (int)((cg >> 4) & 3), j = (int)(cg & 15);
    int n = g * 1024 + (c << 4) + j;
    unsigned short tmp[8];
#pragma unroll
    for (int q = 0; q < 8; ++q) {
      int k = kb + q;
      float v = (k < 512) ? kern[(size_t)k * G4U_ + n] : rkern[(size_t)(k - 512) * G4U_ + n];
      tmp[q] = f2b(v);
    }
    *(int4*)&g_Wt[cg * K_ + kb] = *(const int4*)tmp;
  }

  // Wd transposed
  const size_t nd = (size_t)O_ * (U_ / 8);
  for (size_t i = tid; i < nd; i += np) {
    int o  = (int)(i >> 7);
    int ub = (int)(i & 127) * 8;
    unsigned short tmp[8];
#pragma unroll
    for (int q = 0; q < 8; ++q) tmp[q] = f2b(Wd[(size_t)(ub + q) * O_ + o]);
    *(int4*)&g_Wdt[(size_t)o * U_ + ub] = *(const int4*)tmp;
  }

  // h0 -> bf16 buffer 0
  const size_t nh = (size_t)B_ * U_;
  for (size_t i = tid; i < nh; i += np) g_h[0][i] = f2b(h0[i]);
}

// 128 persistent blocks x 256 threads (4 waves). Block b: rows m0=(b>>5)*32,
// u-cols u0=(b&31)*32. Wave w: rowtile rt=w>>1, utile us=w&1 -> 16 rows x 16 u,
// ALL 4 gates in-wave (4 pure-gate MFMA col-tiles) -> c/h update fully
// in-register, no cross-wave exchange. XCD = b%8 = ugrp%8 -> W slice/XCD
// = 1.57 MB, L2-resident.
__global__ __launch_bounds__(256, 1) void lstm_kernel(const float* __restrict__ c0,
                                                      const float* __restrict__ bias,
                                                      const float* __restrict__ bd,
                                                      float* __restrict__ out) {
  const int b    = blockIdx.x;
  const int tid  = threadIdx.x;
  const int w    = tid >> 6;
  const int lane = tid & 63;
  const int rg   = lane >> 4;   // row-group (C layout) and k-subgroup selector
  const int fr   = lane & 15;
  const int fk   = rg * 8;

  const int m0   = (b >> 5) * 32;
  const int ugrp = b & 31;
  const int u0   = ugrp * 32;
  const int rt   = w >> 1, us = w & 1;
  const int mw   = m0 + rt * 16;
  const int uw   = u0 + us * 16;
  const int cg16 = uw >> 4;

  __shared__ __align__(16) unsigned short Ast[32 * APITCH];  // 98.8 KB
  __shared__ float po[4][16][20];                             // out-proj partials (padded)

  // W row pointers for the 4 gates (B-fragment: row = z-col index, k contiguous)
  const unsigned short* wb[4];
#pragma unroll
  for (int g = 0; g < 4; ++g)
    wb[g] = &g_Wt[(size_t)(cg16 * 64 + g * 16 + fr) * K_ + fk];

  // cell state: 4 elements per lane (rows mw+rg*4+0..3, col uw+fr)
  const int crow = mw + rg * 4;
  f32x4 cv;
#pragma unroll
  for (int r = 0; r < 4; ++r) cv[r] = c0[(size_t)(crow + r) * U_ + uw + fr];
  float bias_v[4];
#pragma unroll
  for (int g = 0; g < 4; ++g) bias_v[g] = bias[g * 1024 + uw + fr];

  // out-projection: block handles 2 tiles: rows ro..+16, cols oc0+{0,16}..+16
  const int ro  = (b >> 4) * 16;
  const int oc0 = (b & 15) * 32;
  const int os  = w >> 1;   // tile select
  const int kq  = w & 1;    // K half
  const int orow = tid >> 4, ocl = tid & 15;
  float bd_v[2];
#pragma unroll
  for (int j = 0; j < 2; ++j) bd_v[j] = bd[oc0 + j * 16 + ocl];

  const unsigned short* arow = &Ast[(size_t)(rt * 16 + fr) * APITCH + fk];

  int cur = 0;
  for (int t = 0; t < T_; ++t) {
    // ---------- stage A = [x_t | h] (32 rows x 1536 k) into LDS, one shot ----------
    {
      const unsigned short* hcur = g_h[cur];
      const int r = tid >> 3, c = tid & 7;
      const int4* sx = (const int4*)&g_xbf[((size_t)(m0 + r) * T_ + t) * D_ + c * 64];
      const int4* sh = (const int4*)&hcur[(size_t)(m0 + r) * U_ + c * 128];
      int4 vx[8], vh[16];
#pragma unroll
      for (int q = 0; q < 8; ++q) vx[q] = sx[q];
#pragma unroll
      for (int q = 0; q < 16; ++q) vh[q] = sh[q];
      int4* dx = (int4*)&Ast[(size_t)r * APITCH + c * 64];
      int4* dh = (int4*)&Ast[(size_t)r * APITCH + 512 + c * 128];
#pragma unroll
      for (int q = 0; q < 8; ++q) dx[q] = vx[q];
#pragma unroll
      for (int q = 0; q < 16; ++q) dh[q] = vh[q];
    }
    __syncthreads();

    // ---------- z = A @ W, 4 gates in-wave, K=1536 ----------
    f32x4 az0 = {0.f, 0.f, 0.f, 0.f}, az1 = {0.f, 0.f, 0.f, 0.f};
    f32x4 az2 = {0.f, 0.f, 0.f, 0.f}, az3 = {0.f, 0.f, 0.f, 0.f};
#pragma unroll 4
    for (int kt = 0; kt < 48; ++kt) {
      const int ko = kt * 32;
      short8 a = *(const short8*)&arow[ko];
      az0 = __builtin_amdgcn_mfma_f32_16x16x32_bf16(a, *(const short8*)&wb[0][ko], az0, 0, 0, 0);
      az1 = __builtin_amdgcn_mfma_f32_16x16x32_bf16(a, *(const short8*)&wb[1][ko], az1, 0, 0, 0);
      az2 = __builtin_amdgcn_mfma_f32_16x16x32_bf16(a, *(const short8*)&wb[2][ko], az2, 0, 0, 0);
      az3 = __builtin_amdgcn_mfma_f32_16x16x32_bf16(a, *(const short8*)&wb[3][ko], az3, 0, 0, 0);
    }

    // ---------- gates + state update (all in-register) ----------
    {
      unsigned short* hn = g_h[cur ^ 1];
#pragma unroll
      for (int r = 0; r < 4; ++r) {
        float zi = az0[r] + bias_v[0];
        float zf = az1[r] + bias_v[1];
        float zg = az2[r] + bias_v[2];
        float zo = az3[r] + bias_v[3];
        float ig = 1.f / (1.f + __expf(-zi));
        float fg = 1.f / (1.f + __expf(-zf));
        float og = 1.f / (1.f + __expf(-zo));
        float gg = tanhf(zg);
        cv[r] = fg * cv[r] + ig * gg;
        float hv = og * tanhf(cv[r]);
        hn[(size_t)(crow + r) * U_ + uw + fr] = f2b(hv);
      }
    }
    __syncthreads();   // all h stores of this block issued

    // ---------- distributed grid barrier: arrive -> gather(block 0) -> release ----------
    if (tid == 0) {
      __threadfence();
      __hip_atomic_store(&g_arrive[b * 32], (unsigned)(t + 1), __ATOMIC_RELEASE,
                         __HIP_MEMORY_SCOPE_AGENT);
    }
    if (b == 0) {
      if (tid < NBLK) {
        while (__hip_atomic_load(&g_arrive[tid * 32], __ATOMIC_ACQUIRE,
                                 __HIP_MEMORY_SCOPE_AGENT) < (unsigned)(t + 1))
          __builtin_amdgcn_s_sleep(1);
      }
      __syncthreads();
      if (tid == 0)
        __hip_atomic_store(&g_release, (unsigned)(t + 1), __ATOMIC_RELEASE,
                           __HIP_MEMORY_SCOPE_AGENT);
    }
    if (tid == 0) {
      while (__hip_atomic_load(&g_release, __ATOMIC_ACQUIRE,
                               __HIP_MEMORY_SCOPE_AGENT) < (unsigned)(t + 1))
        __builtin_amdgcn_s_sleep(1);
    }
    __syncthreads();

    // ---------- out_t = h_t @ Wd + bd: 2 tiles, K split over wave pairs ----------
    {
      const unsigned short* hnew = g_h[cur ^ 1];
      f32x4 oa = {0.f, 0.f, 0.f, 0.f};
      const int kb = kq * 512;
      const unsigned short* ha = &hnew[(size_t)(ro + fr) * U_ + kb + fk];
      const unsigned short* wa = &g_Wdt[(size_t)(oc0 + os * 16 + fr) * U_ + kb + fk];
#pragma unroll
      for (int s = 0; s < 16; ++s) {
        const int k = s * 32;
        oa = __builtin_amdgcn_mfma_f32_16x16x32_bf16(*(const short8*)&ha[k],
                                                     *(const short8*)&wa[k], oa, 0, 0, 0);
      }
#pragma unroll
      for (int r = 0; r < 4; ++r) po[w][rg * 4 + r][fr] = oa[r];
      __syncthreads();
#pragma unroll
      for (int j = 0; j < 2; ++j) {
        float v = po[j * 2][orow][ocl] + po[j * 2 + 1][orow][ocl] + bd_v[j];
        out[((size_t)(ro + orow) * T_ + t) * O_ + oc0 + j * 16 + ocl] = v;
      }
      __syncthreads();
    }
    cur ^= 1;
  }
}

extern "C" void kernel_launch(void* const* d_in, const int* in_sizes, int n_in,
                              void* d_out, int out_size, void* d_ws, size_t ws_size,
                              hipStream_t stream) {
  const float* x    = (const float*)d_in[0];
  const float* h0   = (const float*)d_in[1];
  const float* c0   = (const float*)d_in[2];
  const float* kern = (const float*)d_in[3];
  const float* rk   = (const float*)d_in[4];
  const float* bias = (const float*)d_in[5];
  const float* Wd   = (const float*)d_in[6];
  const float* bd   = (const float*)d_in[7];
  float* out = (float*)d_out;
  (void)in_sizes; (void)n_in; (void)d_ws; (void)ws_size; (void)out_size;

  prep_kernel<<<dim3(1024), dim3(256), 0, stream>>>(x, h0, kern, rk, Wd);
  lstm_kernel<<<dim3(NBLK), dim3(256), 0, stream>>>(c0, bias, bd, out);
}

// Round 3
// 16676.332 us; speedup vs baseline: 1.3569x; 1.3569x over previous
//
#include <hip/hip_runtime.h>
#include <hip/hip_bf16.h>

#define B_   128
#define T_   512
#define D_   512
#define U_   1024
#define O_   512
#define K_   1536      // D + U
#define G4U_ 4096
#define NBLK 128
#define APITCH 1544    // LDS A-row pitch in shorts (dword stride 772 ≡ 4 mod 32)

typedef __attribute__((ext_vector_type(8))) short short8;
typedef __attribute__((ext_vector_type(4))) float f32x4;
typedef __attribute__((ext_vector_type(4))) int int4v;

__device__ __align__(16) unsigned short g_xbf[(size_t)B_ * T_ * D_];   // x bf16 [b][t][d]
__device__ __align__(16) unsigned short g_Wt[(size_t)G4U_ * K_];       // W^T gate-grouped [cg][k]
__device__ __align__(16) unsigned short g_Wdt[(size_t)O_ * U_];        // Wd^T [o][u]
__device__ __align__(16) unsigned short g_h[2][(size_t)B_ * U_];       // double-buffered h (bf16)
__device__ unsigned int g_arrive[NBLK * 32];                            // 1 word / 128 B line
__device__ unsigned int g_release;

__device__ __forceinline__ unsigned short f2b(float f) {
  unsigned u = __float_as_uint(f);
  u += 0x7fffu + ((u >> 16) & 1u);   // RNE
  return (unsigned short)(u >> 16);
}

__global__ void prep_kernel(const float* __restrict__ x, const float* __restrict__ h0,
                            const float* __restrict__ kern, const float* __restrict__ rkern,
                            const float* __restrict__ Wd) {
  size_t tid = (size_t)blockIdx.x * blockDim.x + threadIdx.x;
  size_t np  = (size_t)gridDim.x * blockDim.x;
  if (tid < NBLK * 32) g_arrive[tid] = 0u;
  if (tid == 0) g_release = 0u;

  const size_t nx8 = (size_t)B_ * T_ * D_ / 8;
  const float4* xv = (const float4*)x;
  for (size_t i = tid; i < nx8; i += np) {
    float4 v0 = xv[2 * i], v1 = xv[2 * i + 1];
    unsigned short tmp[8];
    tmp[0] = f2b(v0.x); tmp[1] = f2b(v0.y); tmp[2] = f2b(v0.z); tmp[3] = f2b(v0.w);
    tmp[4] = f2b(v1.x); tmp[5] = f2b(v1.y); tmp[6] = f2b(v1.z); tmp[7] = f2b(v1.w);
    *(int4*)&g_xbf[i * 8] = *(const int4*)tmp;
  }

  // W layout (verified r1/r2): row cg = (u>>4)*64 + gate*16 + (u&15), k contiguous
  const size_t nw = (size_t)G4U_ * (K_ / 8);
  for (size_t i = tid; i < nw; i += np) {
    size_t cg = i / (K_ / 8);
    int kb = (int)(i % (K_ / 8)) * 8;
    int c = (int)(cg >> 6), g = (int)((cg >> 4) & 3), j = (int)(cg & 15);
    int n = g * 1024 + (c << 4) + j;
    unsigned short tmp[8];
#pragma unroll
    for (int q = 0; q < 8; ++q) {
      int k = kb + q;
      float v = (k < 512) ? kern[(size_t)k * G4U_ + n] : rkern[(size_t)(k - 512) * G4U_ + n];
      tmp[q] = f2b(v);
    }
    *(int4*)&g_Wt[cg * K_ + kb] = *(const int4*)tmp;
  }

  const size_t nd = (size_t)O_ * (U_ / 8);
  for (size_t i = tid; i < nd; i += np) {
    int o  = (int)(i >> 7);
    int ub = (int)(i & 127) * 8;
    unsigned short tmp[8];
#pragma unroll
    for (int q = 0; q < 8; ++q) tmp[q] = f2b(Wd[(size_t)(ub + q) * O_ + o]);
    *(int4*)&g_Wdt[(size_t)o * U_ + ub] = *(const int4*)tmp;
  }

  const size_t nh = (size_t)B_ * U_;
  for (size_t i = tid; i < nh; i += np) g_h[0][i] = f2b(h0[i]);
}

// 128 persistent blocks x 256 threads. Block b: rows m0=(b>>5)*32, u0=(b&31)*32.
// Wave w: rows rt=w>>1, u-half us=w&1 -> 16x16 patch, all 4 gates in-register.
// Cross-block h exchange via volatile (sc0|sc1 -> MALL-coherent) accesses;
// barrier flags via RELAXED agent atomics -> NO buffer_inv / buffer_wbl2 storms.
__global__ __launch_bounds__(256, 1) void lstm_kernel(const float* __restrict__ c0,
                                                      const float* __restrict__ bias,
                                                      const float* __restrict__ bd,
                                                      float* __restrict__ out) {
  const int b    = blockIdx.x;
  const int tid  = threadIdx.x;
  const int w    = tid >> 6;
  const int lane = tid & 63;
  const int rg   = lane >> 4;
  const int fr   = lane & 15;
  const int fk   = rg * 8;

  const int m0   = (b >> 5) * 32;
  const int ugrp = b & 31;
  const int u0   = ugrp * 32;
  const int rt   = w >> 1, us = w & 1;
  const int mw   = m0 + rt * 16;
  const int uw   = u0 + us * 16;
  const int cg16 = uw >> 4;

  __shared__ __align__(16) unsigned short Ast[32 * APITCH];
  __shared__ float po[4][16][20];

  const unsigned short* wb[4];
#pragma unroll
  for (int g = 0; g < 4; ++g)
    wb[g] = &g_Wt[(size_t)(cg16 * 64 + g * 16 + fr) * K_ + fk];

  const int crow = mw + rg * 4;
  f32x4 cv;
#pragma unroll
  for (int r = 0; r < 4; ++r) cv[r] = c0[(size_t)(crow + r) * U_ + uw + fr];
  float bias_v[4];
#pragma unroll
  for (int g = 0; g < 4; ++g) bias_v[g] = bias[g * 1024 + uw + fr];

  const int ro  = (b >> 4) * 16;
  const int oc0 = (b & 15) * 32;
  const int os  = w >> 1;
  const int kq  = w & 1;
  const int orow = tid >> 4, ocl = tid & 15;
  float bd_v[2];
#pragma unroll
  for (int j = 0; j < 2; ++j) bd_v[j] = bd[oc0 + j * 16 + ocl];

  const unsigned short* arow = &Ast[(size_t)(rt * 16 + fr) * APITCH + fk];
  const int sr = tid >> 3, sc = tid & 7;   // staging: row, chunk-lane

  // pre-stage x for t=0 (strided chunks: lane sc owns chunks q*8+sc -> bank-clean)
  {
    const unsigned short* sx = &g_xbf[((size_t)(m0 + sr) * T_ + 0) * D_];
    int4v bx[8];
#pragma unroll
    for (int q = 0; q < 8; ++q) bx[q] = *(const int4v*)&sx[q * 64 + sc * 8];
#pragma unroll
    for (int q = 0; q < 8; ++q) *(int4v*)&Ast[(size_t)sr * APITCH + q * 64 + sc * 8] = bx[q];
  }

  int cur = 0;
  for (int t = 0; t < T_; ++t) {
    // ---------- stage h (volatile: MALL-coherent reads) ----------
    {
      const unsigned short* hc = g_h[cur];
      int4v bh[16];
#pragma unroll
      for (int q = 0; q < 16; ++q)
        bh[q] = *(volatile const int4v*)&hc[(size_t)(m0 + sr) * U_ + q * 64 + sc * 8];
#pragma unroll
      for (int q = 0; q < 16; ++q)
        *(int4v*)&Ast[(size_t)sr * APITCH + 512 + q * 64 + sc * 8] = bh[q];
    }
    __syncthreads();

    // ---------- z = A @ W, 4 gates in-register, K=1536 ----------
    f32x4 az0 = {0.f, 0.f, 0.f, 0.f}, az1 = {0.f, 0.f, 0.f, 0.f};
    f32x4 az2 = {0.f, 0.f, 0.f, 0.f}, az3 = {0.f, 0.f, 0.f, 0.f};
#pragma unroll 4
    for (int kt = 0; kt < 48; ++kt) {
      const int ko = kt * 32;
      short8 a = *(const short8*)&arow[ko];
      az0 = __builtin_amdgcn_mfma_f32_16x16x32_bf16(a, *(const short8*)&wb[0][ko], az0, 0, 0, 0);
      az1 = __builtin_amdgcn_mfma_f32_16x16x32_bf16(a, *(const short8*)&wb[1][ko], az1, 0, 0, 0);
      az2 = __builtin_amdgcn_mfma_f32_16x16x32_bf16(a, *(const short8*)&wb[2][ko], az2, 0, 0, 0);
      az3 = __builtin_amdgcn_mfma_f32_16x16x32_bf16(a, *(const short8*)&wb[3][ko], az3, 0, 0, 0);
    }

    // ---------- gates + state update; h stores volatile (write-through) ----------
    {
      unsigned short* hn = g_h[cur ^ 1];
#pragma unroll
      for (int r = 0; r < 4; ++r) {
        float zi = az0[r] + bias_v[0];
        float zf = az1[r] + bias_v[1];
        float zg = az2[r] + bias_v[2];
        float zo = az3[r] + bias_v[3];
        float ig = 1.f / (1.f + __expf(-zi));
        float fg = 1.f / (1.f + __expf(-zf));
        float og = 1.f / (1.f + __expf(-zo));
        float gg = tanhf(zg);
        cv[r] = fg * cv[r] + ig * gg;
        float hv = og * tanhf(cv[r]);
        *(volatile unsigned short*)&hn[(size_t)(crow + r) * U_ + uw + fr] = f2b(hv);
      }
    }
    __syncthreads();   // drains vmcnt(0): all waves' h stores are at the MALL

    // ---------- arrive (relaxed: no cache maintenance) ----------
    if (tid == 0)
      __hip_atomic_store(&g_arrive[b * 32], (unsigned)(t + 1), __ATOMIC_RELAXED,
                         __HIP_MEMORY_SCOPE_AGENT);

    // ---------- overlap: stage x for t+1 while barrier settles ----------
    if (t + 1 < T_) {
      const unsigned short* sx = &g_xbf[((size_t)(m0 + sr) * T_ + (t + 1)) * D_];
      int4v bx[8];
#pragma unroll
      for (int q = 0; q < 8; ++q) bx[q] = *(const int4v*)&sx[q * 64 + sc * 8];
#pragma unroll
      for (int q = 0; q < 8; ++q) *(int4v*)&Ast[(size_t)sr * APITCH + q * 64 + sc * 8] = bx[q];
    }

    // ---------- gather (block 0) + release, all relaxed ----------
    if (b == 0) {
      if (tid < NBLK) {
        while (__hip_atomic_load(&g_arrive[tid * 32], __ATOMIC_RELAXED,
                                 __HIP_MEMORY_SCOPE_AGENT) < (unsigned)(t + 1))
          __builtin_amdgcn_s_sleep(1);
      }
      __syncthreads();
      if (tid == 0)
        __hip_atomic_store(&g_release, (unsigned)(t + 1), __ATOMIC_RELAXED,
                           __HIP_MEMORY_SCOPE_AGENT);
    }
    if (tid == 0) {
      while (__hip_atomic_load(&g_release, __ATOMIC_RELAXED,
                               __HIP_MEMORY_SCOPE_AGENT) < (unsigned)(t + 1))
        __builtin_amdgcn_s_sleep(1);
    }
    __syncthreads();

    // ---------- out_t = h_{t+1} @ Wd + bd ----------
    {
      const unsigned short* hnew = g_h[cur ^ 1];
      f32x4 oa = {0.f, 0.f, 0.f, 0.f};
      const int kb = kq * 512;
      const unsigned short* ha = &hnew[(size_t)(ro + fr) * U_ + kb + fk];
      const unsigned short* wa = &g_Wdt[(size_t)(oc0 + os * 16 + fr) * U_ + kb + fk];
#pragma unroll
      for (int s = 0; s < 16; ++s) {
        const int k = s * 32;
        short8 a = *(volatile const short8*)&ha[k];
        oa = __builtin_amdgcn_mfma_f32_16x16x32_bf16(a, *(const short8*)&wa[k], oa, 0, 0, 0);
      }
#pragma unroll
      for (int r = 0; r < 4; ++r) po[w][rg * 4 + r][fr] = oa[r];
      __syncthreads();
#pragma unroll
      for (int j = 0; j < 2; ++j) {
        float v = po[j * 2][orow][ocl] + po[j * 2 + 1][orow][ocl] + bd_v[j];
        out[((size_t)(ro + orow) * T_ + t) * O_ + oc0 + j * 16 + ocl] = v;
      }
    }
    cur ^= 1;
  }
}

extern "C" void kernel_launch(void* const* d_in, const int* in_sizes, int n_in,
                              void* d_out, int out_size, void* d_ws, size_t ws_size,
                              hipStream_t stream) {
  const float* x    = (const float*)d_in[0];
  const float* h0   = (const float*)d_in[1];
  const float* c0   = (const float*)d_in[2];
  const float* kern = (const float*)d_in[3];
  const float* rk   = (const float*)d_in[4];
  const float* bias = (const float*)d_in[5];
  const float* Wd   = (const float*)d_in[6];
  const float* bd   = (const float*)d_in[7];
  float* out = (float*)d_out;
  (void)in_sizes; (void)n_in; (void)d_ws; (void)ws_size; (void)out_size;

  prep_kernel<<<dim3(1024), dim3(256), 0, stream>>>(x, h0, kern, rk, Wd);
  lstm_kernel<<<dim3(NBLK), dim3(256), 0, stream>>>(c0, bias, bd, out);
}